// Round 6
// baseline (304.057 us; speedup 1.0000x reference)
//
#include <hip/hip_runtime.h>
#include <hip/hip_bf16.h>
#include <math.h>

#define N_NODES   15000
#define N_EDGES   60000
#define EVOCAB    54
#define NODE_INDIM 64
#define EDGE_INDIM 32
#define H  32
#define EH 64
#define N_BOND 4

// setup task ranges (vocab 55296 = 216 blocks exact; proj block-aligned)
#define TASK_VOCAB (EVOCAB * 1024)   // 55296
#define TASK_PROJ  (N_NODES * H)     // 480000
#define TASK_PACK  (3 * H * H)       // 3072
#define TASK_ZDEG  (N_NODES)         // 15000
#define TA (TASK_VOCAB + TASK_PROJ + TASK_PACK + TASK_ZDEG)   // 553368

// ---------------------------------------------------------------------------
// Setup: (a) vocab table packed as Wq[v][i>>2][o][i&3] (float4 per (c,o):
//            4 consecutive-i weights of column o -> coalesced float4 loads)
//        (b) h0 = relu(nf@Wp.T+bp), plus ps0/pd0 attention dots
//        (c) GRU weights packed transposed  (d) zero deg
// ---------------------------------------------------------------------------
__global__ void setup_kernel(const int* __restrict__ node_ids,
                             const float* __restrict__ node_table,
                             const float* __restrict__ edge_table,
                             const float* __restrict__ proj_W, const float* __restrict__ proj_b,
                             const float* __restrict__ attn_w,
                             const float* __restrict__ e1_W1, const float* __restrict__ e1_b1,
                             const float* __restrict__ e1_W2, const float* __restrict__ e1_b2,
                             const float* __restrict__ e2_W1, const float* __restrict__ e2_b1,
                             const float* __restrict__ e2_W2, const float* __restrict__ e2_b2,
                             const float* __restrict__ gWih, const float* __restrict__ gWhh,
                             float* __restrict__ Wq, float* __restrict__ h,
                             float* __restrict__ ps, float* __restrict__ pd,
                             float4* __restrict__ Wpk4, float2* __restrict__ Wpk2,
                             int* __restrict__ deg) {
    int t = blockIdx.x * 256 + threadIdx.x;
    if (t >= TA) return;
    if (t < TASK_VOCAB) {
        int v = t >> 10, f = t & 1023, l = t & 63;   // v wave-uniform (1024 % 64 == 0)
        const float* W1 = (v < N_BOND) ? e1_W1 : e2_W1;
        const float* b1 = (v < N_BOND) ? e1_b1 : e2_b1;
        const float* W2 = (v < N_BOND) ? e1_W2 : e2_W2;
        const float* b2 = (v < N_BOND) ? e1_b2 : e2_b2;
        const float4* ef4 = (const float4*)(edge_table + v * EDGE_INDIM);
        // lane l computes z[l]  (EH == 64 == wave size)
        const float4* w1r = (const float4*)(W1 + l * EDGE_INDIM);
        float z = b1[l];
        #pragma unroll
        for (int c = 0; c < 8; ++c) {
            float4 e4 = ef4[c], w4 = w1r[c];
            z += e4.x * w4.x + e4.y * w4.y + e4.z * w4.z + e4.w * w4.w;
        }
        z = fmaxf(z, 0.f);
        const float4* w2r = (const float4*)(W2 + f * EH);
        float y = b2[f];
        #pragma unroll
        for (int c = 0; c < 16; ++c) {
            float4 w4 = w2r[c];
            y += __shfl(z, 4 * c,     64) * w4.x;
            y += __shfl(z, 4 * c + 1, 64) * w4.y;
            y += __shfl(z, 4 * c + 2, 64) * w4.z;
            y += __shfl(z, 4 * c + 3, 64) * w4.w;
        }
        int i = f >> 5, o = f & 31;                  // f = i*32 + o
        Wq[v * 1024 + (i >> 2) * 128 + o * 4 + (i & 3)] = y;
    } else if (t < TASK_VOCAB + TASK_PROJ) {
        int q = t - TASK_VOCAB;
        int n = q >> 5, o = q & 31;
        int gid = node_ids[n];
        const float4* nf4 = (const float4*)(node_table + (size_t)gid * NODE_INDIM);
        const float4* wr4 = (const float4*)(proj_W + o * NODE_INDIM);
        float acc = proj_b[o];
        #pragma unroll
        for (int c = 0; c < 16; ++c) {
            float4 a = nf4[c], w = wr4[c];
            acc += a.x * w.x + a.y * w.y + a.z * w.z + a.w * w.w;
        }
        acc = fmaxf(acc, 0.f);
        h[q] = acc;
        // attention dots for step 0 (once per node, not per edge)
        float v0 = acc * attn_w[o], v1 = acc * attn_w[32 + o];
        #pragma unroll
        for (int m = 16; m > 0; m >>= 1) {
            v0 += __shfl_xor(v0, m, 32);
            v1 += __shfl_xor(v1, m, 32);
        }
        if (o == 0) { ps[n] = v0; pd[n] = v1; }
    } else if (t < TASK_VOCAB + TASK_PROJ + TASK_PACK) {
        int q = t - TASK_VOCAB - TASK_PROJ;          // q = j*32 + o
        int j = q >> 5, o = q & 31;
        Wpk4[q] = make_float4(gWih[o * 32 + j], gWih[(32 + o) * 32 + j],
                              gWih[(64 + o) * 32 + j], gWhh[o * 32 + j]);
        Wpk2[q] = make_float2(gWhh[(32 + o) * 32 + j], gWhh[(64 + o) * 32 + j]);
    } else {
        deg[t - TASK_VOCAB - TASK_PROJ - TASK_PACK] = 0;
    }
}

// ---------------------------------------------------------------------------
// CSR build: histogram (+rank), 1-block scan, scatter packed (src,vocab).
// ---------------------------------------------------------------------------
__global__ void hist_kernel(const int* __restrict__ dst, int* __restrict__ deg,
                            int* __restrict__ rank) {
    int e = blockIdx.x * 256 + threadIdx.x;
    if (e < N_EDGES) rank[e] = atomicAdd(&deg[dst[e]], 1);
}

__global__ void scan_kernel(const int* __restrict__ deg, int* __restrict__ off) {
    __shared__ int lsum[256];
    int t = threadIdx.x;
    int beg = t * 59, end = min(beg + 59, N_NODES);
    int s = 0;
    for (int i = beg; i < end; ++i) s += deg[i];
    lsum[t] = s;
    __syncthreads();
    for (int d2 = 1; d2 < 256; d2 <<= 1) {
        int v = (t >= d2) ? lsum[t - d2] : 0;
        __syncthreads();
        lsum[t] += v;
        __syncthreads();
    }
    int run = lsum[t] - s;
    if (t == 0) off[0] = 0;
    for (int i = beg; i < end; ++i) { run += deg[i]; off[i + 1] = run; }
}

__global__ void scatter_kernel(const int* __restrict__ dst, const int* __restrict__ src,
                               const int* __restrict__ edge_ids,
                               const int* __restrict__ off, const int* __restrict__ rank,
                               int2* __restrict__ esv) {
    int e = blockIdx.x * 256 + threadIdx.x;
    if (e < N_EDGES) esv[off[dst[e]] + rank[e]] = make_int2(src[e], edge_ids[e]);
}

// ---------------------------------------------------------------------------
// Fused step: per-node gather (attention via precomputed ps/pd + message),
// softmax normalize, GRU, and epilogue ps/pd for the next step.
// No atomics, no shuffles in the edge loop.
// ---------------------------------------------------------------------------
__launch_bounds__(256)
__global__ void step_kernel(const float* __restrict__ hcur,
                            const float* __restrict__ ps_in, const float* __restrict__ pd_in,
                            const int* __restrict__ off, const int2* __restrict__ esv,
                            const float* __restrict__ Wq, const float* __restrict__ attn_w,
                            const float4* __restrict__ Wpk4, const float2* __restrict__ Wpk2,
                            const float* __restrict__ gbih, const float* __restrict__ gbhh,
                            float* __restrict__ hout,
                            float* __restrict__ ps_out, float* __restrict__ pd_out) {
    __shared__ float lm[8][32], lh[8][32];
    int t = blockIdx.x * 256 + threadIdx.x;          // t < 480000
    int n = t >> 5, o = t & 31, g = threadIdx.x >> 5;
    float hd  = hcur[n * 32 + o];
    float pdn = pd_in[n];
    float num = 0.f, den = 0.f;
    int k1 = off[n + 1];
    for (int k = off[n]; k < k1; ++k) {
        int2 sv = esv[k];                            // group-uniform broadcast load
        float a = ps_in[sv.x] + pdn;
        a = (a > 0.f) ? a : 0.01f * a;               // leaky_relu slope 0.01
        float ex = __expf(a);
        const float4* hrow = (const float4*)(hcur + sv.x * 32);   // 8x uniform f4
        const float4* W4   = (const float4*)(Wq + sv.y * 1024) + o; // + c*32: coalesced
        float y = 0.f;
        #pragma unroll
        for (int c = 0; c < 8; ++c) {
            float4 h4 = hrow[c];
            float4 w4 = W4[c * 32];                  // (W[4c..4c+3][o])
            y += h4.x * w4.x + h4.y * w4.y + h4.z * w4.z + h4.w * w4.w;
        }
        num += ex * y;
        den += ex;
    }
    float m = (den > 0.f) ? fmaxf(num / den, 0.f) : 0.f;   // deg-0 -> agg 0
    // --- GRU cell: broadcast m,h via LDS rows (same-address b128 reads) ---
    lm[g][o] = m;
    lh[g][o] = hd;                                   // same-wave only: no barrier
    float gir = 0.f, giz = 0.f, gin = 0.f, ghr = 0.f, ghz = 0.f, ghn = 0.f;
    #pragma unroll
    for (int c = 0; c < 8; ++c) {
        float4 m4 = ((const float4*)lm[g])[c];
        float4 h4 = ((const float4*)lh[g])[c];
        #pragma unroll
        for (int u = 0; u < 4; ++u) {
            int j = 4 * c + u;
            float mj = (u == 0) ? m4.x : (u == 1) ? m4.y : (u == 2) ? m4.z : m4.w;
            float hj = (u == 0) ? h4.x : (u == 1) ? h4.y : (u == 2) ? h4.z : h4.w;
            float4 a4 = Wpk4[j * 32 + o];
            float2 b2 = Wpk2[j * 32 + o];
            gir += mj * a4.x;  giz += mj * a4.y;  gin += mj * a4.z;
            ghr += hj * a4.w;  ghz += hj * b2.x;  ghn += hj * b2.y;
        }
    }
    float r  = 1.f / (1.f + __expf(-(gir + gbih[o]      + ghr + gbhh[o])));
    float z  = 1.f / (1.f + __expf(-(giz + gbih[32 + o] + ghz + gbhh[32 + o])));
    float nn = tanhf(gin + gbih[64 + o] + r * (ghn + gbhh[64 + o]));
    float hnew = (1.f - z) * nn + z * hd;
    hout[t] = hnew;
    // --- epilogue: attention dots of the new h for the next step ---
    float v0 = hnew * attn_w[o], v1 = hnew * attn_w[32 + o];
    #pragma unroll
    for (int mm = 16; mm > 0; mm >>= 1) {
        v0 += __shfl_xor(v0, mm, 32);
        v1 += __shfl_xor(v1, mm, 32);
    }
    if (o == 0) { ps_out[n] = v0; pd_out[n] = v1; }
}

// ---------------------------------------------------------------------------
extern "C" void kernel_launch(void* const* d_in, const int* in_sizes, int n_in,
                              void* d_out, int out_size, void* d_ws, size_t ws_size,
                              hipStream_t stream) {
    const int*   node_ids   = (const int*)d_in[0];
    const int*   edge_ids   = (const int*)d_in[1];
    const int*   src        = (const int*)d_in[2];
    const int*   dst        = (const int*)d_in[3];
    const float* node_table = (const float*)d_in[4];
    const float* edge_table = (const float*)d_in[5];
    const float* proj_W     = (const float*)d_in[6];
    const float* proj_b     = (const float*)d_in[7];
    const float* attn_w     = (const float*)d_in[8];
    const float* e1_W1 = (const float*)d_in[9];  const float* e1_b1 = (const float*)d_in[10];
    const float* e1_W2 = (const float*)d_in[11]; const float* e1_b2 = (const float*)d_in[12];
    const float* e2_W1 = (const float*)d_in[13]; const float* e2_b1 = (const float*)d_in[14];
    const float* e2_W2 = (const float*)d_in[15]; const float* e2_b2 = (const float*)d_in[16];
    const float* gWih  = (const float*)d_in[17]; const float* gWhh  = (const float*)d_in[18];
    const float* gbih  = (const float*)d_in[19]; const float* gbhh  = (const float*)d_in[20];

    // workspace (~5.2 MB of the 256 MiB ws)
    char* ws = (char*)d_ws;
    float*  Wq   = (float*)(ws);                     // 221184
    float*  h_a  = (float*)(ws + 221184);            // 1920000
    float*  h_b  = (float*)(ws + 2141184);           // 1920000
    float4* Wpk4 = (float4*)(ws + 4061184);          // 49152
    float2* Wpk2 = (float2*)(ws + 4110336);          // 24576
    float*  ps_a = (float*)(ws + 4134912);           // 60000
    float*  pd_a = (float*)(ws + 4194912);           // 60000
    float*  ps_b = (float*)(ws + 4254912);           // 60000
    float*  pd_b = (float*)(ws + 4314912);           // 60000
    int*    deg  = (int*)(ws + 4374912);             // 60000
    int*    off  = (int*)(ws + 4434912);             // 60004
    int*    rank = (int*)(ws + 4494916);             // 240000
    int2*   esv  = (int2*)(ws + 4734976);            // 480000 (8B aligned)
    float*  out  = (float*)d_out;

    setup_kernel<<<(TA + 255) / 256, 256, 0, stream>>>(
        node_ids, node_table, edge_table, proj_W, proj_b, attn_w,
        e1_W1, e1_b1, e1_W2, e1_b2, e2_W1, e2_b1, e2_W2, e2_b2,
        gWih, gWhh, Wq, h_a, ps_a, pd_a, Wpk4, Wpk2, deg);
    hist_kernel<<<(N_EDGES + 255) / 256, 256, 0, stream>>>(dst, deg, rank);
    scan_kernel<<<1, 256, 0, stream>>>(deg, off);
    scatter_kernel<<<(N_EDGES + 255) / 256, 256, 0, stream>>>(dst, src, edge_ids, off, rank, esv);

    step_kernel<<<1875, 256, 0, stream>>>(h_a, ps_a, pd_a, off, esv, Wq, attn_w,
                                          Wpk4, Wpk2, gbih, gbhh, h_b, ps_b, pd_b);
    step_kernel<<<1875, 256, 0, stream>>>(h_b, ps_b, pd_b, off, esv, Wq, attn_w,
                                          Wpk4, Wpk2, gbih, gbhh, h_a, ps_a, pd_a);
    step_kernel<<<1875, 256, 0, stream>>>(h_a, ps_a, pd_a, off, esv, Wq, attn_w,
                                          Wpk4, Wpk2, gbih, gbhh, out, ps_b, pd_b);
}

// Round 7
// 253.105 us; speedup vs baseline: 1.2013x; 1.2013x over previous
//
#include <hip/hip_runtime.h>
#include <hip/hip_bf16.h>
#include <math.h>

#define N_NODES   15000
#define N_EDGES   60000
#define EVOCAB    54
#define NODE_INDIM 64
#define EDGE_INDIM 32
#define H  32
#define EH 64
#define N_BOND 4

// setup task ranges
#define TASK_VOCAB (EVOCAB * 1024)                  // 55296
#define TASK_PROJ  (N_NODES * H)                    // 480000
#define TASK_PACK  (3 * H * H)                      // 3072
#define TASK_ZERO  ((N_NODES * H + N_NODES) / 4)    // 123750 float4 (agg+sm contiguous)
#define TA (TASK_VOCAB + TASK_PROJ + TASK_PACK + TASK_ZERO)   // 662118

// ---------------------------------------------------------------------------
// Setup: (a) vocab table packed Wq[v][i>>2][o][i&3] -> edge kernel reads
//            4 consecutive-i weights of column o as one coalesced float4
//        (b) h0 = relu(nf@Wp.T+bp) + ps/pd attention dots (per node, step 0)
//        (c) GRU weights packed transposed  (d) zero agg+sm
// ---------------------------------------------------------------------------
__global__ void setup_kernel(const int* __restrict__ node_ids,
                             const float* __restrict__ node_table,
                             const float* __restrict__ edge_table,
                             const float* __restrict__ proj_W, const float* __restrict__ proj_b,
                             const float* __restrict__ attn_w,
                             const float* __restrict__ e1_W1, const float* __restrict__ e1_b1,
                             const float* __restrict__ e1_W2, const float* __restrict__ e1_b2,
                             const float* __restrict__ e2_W1, const float* __restrict__ e2_b1,
                             const float* __restrict__ e2_W2, const float* __restrict__ e2_b2,
                             const float* __restrict__ gWih, const float* __restrict__ gWhh,
                             float* __restrict__ Wq, float* __restrict__ h,
                             float* __restrict__ ps, float* __restrict__ pd,
                             float4* __restrict__ Wpk4, float2* __restrict__ Wpk2,
                             float* __restrict__ agg) {
    int t = blockIdx.x * 256 + threadIdx.x;
    if (t >= TA) return;
    if (t < TASK_VOCAB) {
        int v = t >> 10, f = t & 1023, l = t & 63;   // v wave-uniform (1024 % 64 == 0)
        const float* W1 = (v < N_BOND) ? e1_W1 : e2_W1;
        const float* b1 = (v < N_BOND) ? e1_b1 : e2_b1;
        const float* W2 = (v < N_BOND) ? e1_W2 : e2_W2;
        const float* b2 = (v < N_BOND) ? e1_b2 : e2_b2;
        const float4* ef4 = (const float4*)(edge_table + v * EDGE_INDIM);
        const float4* w1r = (const float4*)(W1 + l * EDGE_INDIM);
        float z = b1[l];                              // lane l owns z[l] (EH == 64)
        #pragma unroll
        for (int c = 0; c < 8; ++c) {
            float4 e4 = ef4[c], w4 = w1r[c];
            z += e4.x * w4.x + e4.y * w4.y + e4.z * w4.z + e4.w * w4.w;
        }
        z = fmaxf(z, 0.f);
        const float4* w2r = (const float4*)(W2 + f * EH);
        float y = b2[f];
        #pragma unroll
        for (int c = 0; c < 16; ++c) {
            float4 w4 = w2r[c];
            y += __shfl(z, 4 * c,     64) * w4.x;
            y += __shfl(z, 4 * c + 1, 64) * w4.y;
            y += __shfl(z, 4 * c + 2, 64) * w4.z;
            y += __shfl(z, 4 * c + 3, 64) * w4.w;
        }
        int i = f >> 5, o = f & 31;                   // f = i*32 + o
        Wq[v * 1024 + (i >> 2) * 128 + o * 4 + (i & 3)] = y;
    } else if (t < TASK_VOCAB + TASK_PROJ) {
        int q = t - TASK_VOCAB;
        int n = q >> 5, o = q & 31;
        int gid = node_ids[n];
        const float4* nf4 = (const float4*)(node_table + (size_t)gid * NODE_INDIM);
        const float4* wr4 = (const float4*)(proj_W + o * NODE_INDIM);
        float acc = proj_b[o];
        #pragma unroll
        for (int c = 0; c < 16; ++c) {
            float4 a = nf4[c], w = wr4[c];
            acc += a.x * w.x + a.y * w.y + a.z * w.z + a.w * w.w;
        }
        acc = fmaxf(acc, 0.f);
        h[q] = acc;
        float v0 = acc * attn_w[o], v1 = acc * attn_w[32 + o];
        #pragma unroll
        for (int m = 16; m > 0; m >>= 1) {
            v0 += __shfl_xor(v0, m, 32);
            v1 += __shfl_xor(v1, m, 32);
        }
        if (o == 0) { ps[n] = v0; pd[n] = v1; }
    } else if (t < TASK_VOCAB + TASK_PROJ + TASK_PACK) {
        int q = t - TASK_VOCAB - TASK_PROJ;           // q = j*32 + o
        int j = q >> 5, o = q & 31;
        Wpk4[q] = make_float4(gWih[o * 32 + j], gWih[(32 + o) * 32 + j],
                              gWih[(64 + o) * 32 + j], gWhh[o * 32 + j]);
        Wpk2[q] = make_float2(gWhh[(32 + o) * 32 + j], gWhh[(64 + o) * 32 + j]);
    } else {
        int q = t - TASK_VOCAB - TASK_PROJ - TASK_PACK;
        ((float4*)agg)[q] = make_float4(0.f, 0.f, 0.f, 0.f);   // agg + sm contiguous
    }
}

// ---------------------------------------------------------------------------
// Edge scatter: one edge per 32-lane group, straight-line (no loop, no serial
// chain). Attention from precomputed ps/pd; unnormalized accumulate:
//   agg[d] += ex * (h_s @ W_v),  sm[d] += ex.
// 1.92M independent threads -> atomics pipeline, latency fully hidden by TLP.
// ---------------------------------------------------------------------------
__launch_bounds__(256)
__global__ void edge_kernel(const int* __restrict__ src, const int* __restrict__ dst,
                            const int* __restrict__ eid,
                            const float* __restrict__ ps, const float* __restrict__ pd,
                            const float* __restrict__ hcur, const float* __restrict__ Wq,
                            float* __restrict__ agg, float* __restrict__ sm) {
    int t = blockIdx.x * 256 + threadIdx.x;
    int e = t >> 5, o = t & 31;
    int s = src[e], d = dst[e], v = eid[e];
    float a = ps[s] + pd[d];
    a = (a > 0.f) ? a : 0.01f * a;                    // leaky_relu slope 0.01
    float ex = __expf(a);
    const float4* hrow = (const float4*)(hcur + s * 32);      // group-uniform bcast
    const float4* W4   = (const float4*)(Wq + v * 1024) + o;  // + c*32: coalesced
    float y = 0.f;
    #pragma unroll
    for (int c = 0; c < 8; ++c) {
        float4 h4 = hrow[c];
        float4 w4 = W4[c * 32];                       // W[4c..4c+3][o]
        y += h4.x * w4.x + h4.y * w4.y + h4.z * w4.z + h4.w * w4.w;
    }
    atomicAdd(&agg[d * 32 + o], ex * y);
    if (o == 0) atomicAdd(&sm[d], ex);
}

// ---------------------------------------------------------------------------
// GRU: m = relu(agg/sm); GRU cell; write h; re-zero agg/sm; next-step ps/pd.
// Broadcast m,h via same-wave LDS rows (no barrier); weights packed so all
// loads are wave-coalesced/broadcast.
// ---------------------------------------------------------------------------
__launch_bounds__(256)
__global__ void gru_kernel(float* __restrict__ agg, float* __restrict__ sm,
                           const float* __restrict__ hcur,
                           const float4* __restrict__ Wpk4, const float2* __restrict__ Wpk2,
                           const float* __restrict__ gbih, const float* __restrict__ gbhh,
                           const float* __restrict__ attn_w,
                           float* __restrict__ hout,
                           float* __restrict__ ps_out, float* __restrict__ pd_out) {
    __shared__ float lm[8][32], lh[8][32];
    int t = blockIdx.x * 256 + threadIdx.x;           // t < 480000
    int n = t >> 5, o = t & 31, g = threadIdx.x >> 5;
    float den = sm[n];
    float m  = (den > 0.f) ? fmaxf(agg[t] / den, 0.f) : 0.f;  // deg-0 -> 0
    float hv = hcur[t];
    lm[g][o] = m;
    lh[g][o] = hv;                                    // same-wave only: no barrier
    float gir = 0.f, giz = 0.f, gin = 0.f, ghr = 0.f, ghz = 0.f, ghn = 0.f;
    #pragma unroll
    for (int c = 0; c < 8; ++c) {
        float4 m4 = ((const float4*)lm[g])[c];
        float4 h4 = ((const float4*)lh[g])[c];
        #pragma unroll
        for (int u = 0; u < 4; ++u) {
            int j = 4 * c + u;
            float mj = (u == 0) ? m4.x : (u == 1) ? m4.y : (u == 2) ? m4.z : m4.w;
            float hj = (u == 0) ? h4.x : (u == 1) ? h4.y : (u == 2) ? h4.z : h4.w;
            float4 a4 = Wpk4[j * 32 + o];
            float2 b2 = Wpk2[j * 32 + o];
            gir += mj * a4.x;  giz += mj * a4.y;  gin += mj * a4.z;
            ghr += hj * a4.w;  ghz += hj * b2.x;  ghn += hj * b2.y;
        }
    }
    float r  = 1.f / (1.f + __expf(-(gir + gbih[o]      + ghr + gbhh[o])));
    float z  = 1.f / (1.f + __expf(-(giz + gbih[32 + o] + ghz + gbhh[32 + o])));
    float nn = tanhf(gin + gbih[64 + o] + r * (ghn + gbhh[64 + o]));
    float hnew = (1.f - z) * nn + z * hv;
    hout[t] = hnew;
    agg[t] = 0.f;                                     // ready for next step
    if (o == 0) sm[n] = 0.f;
    float v0 = hnew * attn_w[o], v1 = hnew * attn_w[32 + o];
    #pragma unroll
    for (int mm = 16; mm > 0; mm >>= 1) {
        v0 += __shfl_xor(v0, mm, 32);
        v1 += __shfl_xor(v1, mm, 32);
    }
    if (o == 0) { ps_out[n] = v0; pd_out[n] = v1; }
}

// ---------------------------------------------------------------------------
extern "C" void kernel_launch(void* const* d_in, const int* in_sizes, int n_in,
                              void* d_out, int out_size, void* d_ws, size_t ws_size,
                              hipStream_t stream) {
    const int*   node_ids   = (const int*)d_in[0];
    const int*   edge_ids   = (const int*)d_in[1];
    const int*   src        = (const int*)d_in[2];
    const int*   dst        = (const int*)d_in[3];
    const float* node_table = (const float*)d_in[4];
    const float* edge_table = (const float*)d_in[5];
    const float* proj_W     = (const float*)d_in[6];
    const float* proj_b     = (const float*)d_in[7];
    const float* attn_w     = (const float*)d_in[8];
    const float* e1_W1 = (const float*)d_in[9];  const float* e1_b1 = (const float*)d_in[10];
    const float* e1_W2 = (const float*)d_in[11]; const float* e1_b2 = (const float*)d_in[12];
    const float* e2_W1 = (const float*)d_in[13]; const float* e2_b1 = (const float*)d_in[14];
    const float* e2_W2 = (const float*)d_in[15]; const float* e2_b2 = (const float*)d_in[16];
    const float* gWih  = (const float*)d_in[17]; const float* gWhh  = (const float*)d_in[18];
    const float* gbih  = (const float*)d_in[19]; const float* gbhh  = (const float*)d_in[20];

    // workspace (~4.3 MB): Wq | h | Wpk4 | Wpk2 | ps | pd | agg | sm (contig)
    char* ws = (char*)d_ws;
    float*  Wq   = (float*)(ws);                      // 221184
    float*  h    = (float*)(ws + 221184);             // 1920000
    float4* Wpk4 = (float4*)(ws + 2141184);           // 49152
    float2* Wpk2 = (float2*)(ws + 2190336);           // 24576
    float*  ps   = (float*)(ws + 2214912);            // 60000
    float*  pd   = (float*)(ws + 2274912);            // 60000
    float*  agg  = (float*)(ws + 2334912);            // 1920000
    float*  sm   = (float*)(ws + 4254912);            // 60000 (right after agg)
    float*  out  = (float*)d_out;

    setup_kernel<<<(TA + 255) / 256, 256, 0, stream>>>(
        node_ids, node_table, edge_table, proj_W, proj_b, attn_w,
        e1_W1, e1_b1, e1_W2, e1_b2, e2_W1, e2_b1, e2_W2, e2_b2,
        gWih, gWhh, Wq, h, ps, pd, Wpk4, Wpk2, agg);

    for (int step = 0; step < 3; ++step) {
        edge_kernel<<<(N_EDGES * 32) / 256, 256, 0, stream>>>(
            src, dst, edge_ids, ps, pd, h, Wq, agg, sm);
        float* hout = (step == 2) ? out : h;          // gru is per-element: in-place ok
        gru_kernel<<<(N_NODES * 32) / 256, 256, 0, stream>>>(
            agg, sm, h, Wpk4, Wpk2, gbih, gbhh, attn_w, hout, ps, pd);
    }
}